// Round 4
// baseline (126.234 us; speedup 1.0000x reference)
//
#include <hip/hip_runtime.h>

using f32x4  = __attribute__((ext_vector_type(4))) float;
using bf16x8 = __attribute__((ext_vector_type(8))) __bf16;

static constexpr int DD = 512;
static constexpr int NTOK = 4096;  // B*V

__device__ __forceinline__ float bf2f(unsigned short u) {
  unsigned int v = ((unsigned int)u) << 16;
  return __builtin_bit_cast(float, v);
}
__device__ __forceinline__ float bflo(unsigned int u) {
  return __builtin_bit_cast(float, u << 16);
}
__device__ __forceinline__ float bfhi(unsigned int u) {
  return __builtin_bit_cast(float, u & 0xffff0000u);
}
__device__ __forceinline__ unsigned short f2bf(float f) {
  unsigned int u = __builtin_bit_cast(unsigned int, f);
  unsigned int r = u + 0x7fffu + ((u >> 16) & 1u);
  return (unsigned short)(r >> 16);
}
__device__ __forceinline__ float lrelu(float v) { return v >= 0.f ? v : 0.2f * v; }

// Fragment-panel layout for (rows,K) consumed as MFMA operand:
// off = (tile16*KS + ks)*512 + ((k>>3)&3)*128 + (row&15)*8 + (k&7)
// A-frag and B-frag have identical linear layouts; wave load = base + lane*16B.

// ---- k_prep: all layout transforms + BN accumulator zeroing, one dispatch ----
__global__ __launch_bounds__(256) void k_prep(const float* __restrict__ F,
                                              const float* __restrict__ W1,
                                              const float* __restrict__ W2,
                                              const float* __restrict__ W3,
                                              const float* __restrict__ Wf,
                                              unsigned short* __restrict__ XP,
                                              unsigned short* __restrict__ W1P,
                                              unsigned short* __restrict__ W2P,
                                              unsigned short* __restrict__ W3P,
                                              unsigned short* __restrict__ WfP,
                                              float* __restrict__ sums) {
  const int bid = blockIdx.x, tid = threadIdx.x;
  if (bid < 8192) {                       // F -> XP (panel layout, ks 0..15 of 32)
    int idx = (bid << 8) + tid;           // 4096*512
    int t = idx >> 9, c = idx & 511;
    XP[((t >> 4) * 32 + (c >> 5)) * 512 + ((c >> 3) & 3) * 128 + (t & 15) * 8 + (c & 7)] = f2bf(F[idx]);
  } else if (bid < 10240) {               // W1 (1024,512) -> W1P fragment order (K=512, N=1024 combined)
    int idx = ((bid - 8192) << 8) + tid;  // 512*1024
    int k = idx >> 10, n = idx & 1023;
    float v = W1[(n < 512 ? k : 512 + k) * 512 + (n & 511)];
    W1P[((n >> 4) * 16 + (k >> 5)) * 512 + ((k >> 3) & 3) * 128 + (n & 15) * 8 + (k & 7)] = f2bf(v);
  } else if (bid < 11264) {               // W2 (512,512) -> W2P
    int idx = ((bid - 10240) << 8) + tid;
    int k = idx >> 9, n = idx & 511;
    W2P[((n >> 4) * 16 + (k >> 5)) * 512 + ((k >> 3) & 3) * 128 + (n & 15) * 8 + (k & 7)] = f2bf(W2[idx]);
  } else if (bid < 12288) {               // W3
    int idx = ((bid - 11264) << 8) + tid;
    int k = idx >> 9, n = idx & 511;
    W3P[((n >> 4) * 16 + (k >> 5)) * 512 + ((k >> 3) & 3) * 128 + (n & 15) * 8 + (k & 7)] = f2bf(W3[idx]);
  } else if (bid < 14336) {               // Wf (1024,512) -> WfP (K=1024)
    int idx = ((bid - 12288) << 8) + tid;
    int k = idx >> 9, n = idx & 511;
    WfP[((n >> 4) * 32 + (k >> 5)) * 512 + ((k >> 3) & 3) * 128 + (n & 15) * 8 + (k & 7)] = f2bf(Wf[idx]);
  } else {                                // zero sums+sumsq (1024 floats)
    reinterpret_cast<float4*>(sums)[tid] = float4{0.f, 0.f, 0.f, 0.f};
  }
}

// ---- GEMM1: ACP = [F@W1a | F@W1b] in panel layout. grid (64,4), 512 thr ----
__global__ __launch_bounds__(512) void k_gemm_ac(const unsigned short* __restrict__ XP,
                                                 const unsigned short* __restrict__ W1P,
                                                 unsigned short* __restrict__ ACP) {
  const int tid = threadIdx.x, lane = tid & 63, wid = tid >> 6;
  const int wm = wid >> 2, wn = wid & 3;
  const int l15 = lane & 15;
  const int bx = blockIdx.x, by = blockIdx.y;

  f32x4 acc[2][4];
#pragma unroll
  for (int mt = 0; mt < 2; ++mt)
#pragma unroll
    for (int nt = 0; nt < 4; ++nt) acc[mt][nt] = f32x4{0.f, 0.f, 0.f, 0.f};

  bf16x8 ca[2], cb[4], na[2], nb[4];
  auto ldA = [&](bf16x8 (&d)[2], int ks) {
#pragma unroll
    for (int mt = 0; mt < 2; ++mt)
      d[mt] = *reinterpret_cast<const bf16x8*>(XP + (((bx * 4 + wm * 2 + mt) * 32 + ks) << 9) + lane * 8);
  };
  auto ldB = [&](bf16x8 (&d)[4], int ks) {
#pragma unroll
    for (int nt = 0; nt < 4; ++nt)
      d[nt] = *reinterpret_cast<const bf16x8*>(W1P + ((((by * 16 + wn * 4 + nt) * 16) + ks) << 9) + lane * 8);
  };

  ldA(ca, 0); ldB(cb, 0);
  for (int ks = 0; ks < 16; ++ks) {
    int kn = (ks + 1) & 15;
    ldA(na, kn); ldB(nb, kn);
    __builtin_amdgcn_s_setprio(1);
#pragma unroll
    for (int mt = 0; mt < 2; ++mt)
#pragma unroll
      for (int nt = 0; nt < 4; ++nt)
        acc[mt][nt] = __builtin_amdgcn_mfma_f32_16x16x32_bf16(ca[mt], cb[nt], acc[mt][nt], 0, 0, 0);
    __builtin_amdgcn_s_setprio(0);
#pragma unroll
    for (int q = 0; q < 2; ++q) ca[q] = na[q];
#pragma unroll
    for (int q = 0; q < 4; ++q) cb[q] = nb[q];
  }
#pragma unroll
  for (int mt = 0; mt < 2; ++mt)
#pragma unroll
    for (int nt = 0; nt < 4; ++nt) {
      int col = by * 256 + wn * 64 + nt * 16 + l15;
      int panel = bx * 4 + wm * 2 + mt;
#pragma unroll
      for (int r = 0; r < 4; ++r) {
        int rowi = (lane >> 4) * 4 + r;
        ACP[(panel * 32 + (col >> 5)) * 512 + ((col >> 3) & 3) * 128 + rowi * 8 + (col & 7)] = f2bf(acc[mt][nt][r]);
      }
    }
}

// ---- relation: block = (b, half) -> 8 tokens x 16 j = 128 relrows ----
// Operand-swapped: h2^T = W2^T @ h1^T. Wave grid 4(feature) x 2(relrow).
// h kept in LDS in fragment-panel layout: all LDS accesses conflict-free.
__global__ __launch_bounds__(512, 2) void k_relation(const unsigned short* __restrict__ ACP,
                                                     const unsigned short* __restrict__ W2P,
                                                     const unsigned short* __restrict__ W3P,
                                                     const float* __restrict__ b1,
                                                     const float* __restrict__ b2,
                                                     const float* __restrict__ b3,
                                                     unsigned short* __restrict__ XP) {
  __shared__ unsigned short lds[65536];  // 8 relrow-tiles x 16 ks x 512 el = 128 KB
  const int tid = threadIdx.x;
  const int b = blockIdx.x >> 1, half = blockIdx.x & 1;

  // ---- phase 0: h1 = lrelu(A_i + C_j + b1) -> LDS panel ----
  {
    const int r = tid >> 2;              // relrow 0..127 = il*16 + j
    const int il = r >> 4, j = r & 15;
    const int rowA = half * 8 + il;
    const int kq = tid & 3;
#pragma unroll
    for (int ks = 0; ks < 16; ++ks) {
      const int c = ks * 32 + kq * 8;
      uint4 av = *reinterpret_cast<const uint4*>(ACP + ((b * 32 + ks) << 9) + kq * 128 + rowA * 8);
      uint4 cv = *reinterpret_cast<const uint4*>(ACP + ((b * 32 + 16 + ks) << 9) + kq * 128 + j * 8);
      float4 bv0 = *reinterpret_cast<const float4*>(b1 + c);
      float4 bv1 = *reinterpret_cast<const float4*>(b1 + c + 4);
      unsigned int au[4] = {av.x, av.y, av.z, av.w};
      unsigned int cu[4] = {cv.x, cv.y, cv.z, cv.w};
      float bb[8] = {bv0.x, bv0.y, bv0.z, bv0.w, bv1.x, bv1.y, bv1.z, bv1.w};
      unsigned int ou[4];
#pragma unroll
      for (int q = 0; q < 4; ++q) {
        float v0 = lrelu(bflo(au[q]) + bflo(cu[q]) + bb[2 * q]);
        float v1 = lrelu(bf2f((unsigned short)(au[q] >> 16)) +
                         bf2f((unsigned short)(cu[q] >> 16)) + bb[2 * q + 1]);
        ou[q] = ((unsigned int)f2bf(v1) << 16) | (unsigned int)f2bf(v0);
      }
      uint4 o; o.x = ou[0]; o.y = ou[1]; o.z = ou[2]; o.w = ou[3];
      *reinterpret_cast<uint4*>(lds + (((r >> 4) * 16 + ks) << 9) + kq * 128 + (r & 15) * 8) = o;
    }
  }
  __syncthreads();

  const int lane = tid & 63, wid = tid >> 6;
  const int l15 = lane & 15;
  const int fg = wid >> 1;     // feature group 0..3 (128 feats each)
  const int rg = wid & 1;      // relrow group 0..1 (64 relrows each)

  f32x4 acc[8][4];
  bf16x8 ca[8], na[8], cb[4];

  auto ldA = [&](bf16x8 (&d)[8], const unsigned short* __restrict__ Wp, int ks) {
#pragma unroll
    for (int mt = 0; mt < 8; ++mt)
      d[mt] = *reinterpret_cast<const bf16x8*>(Wp + (((fg * 8 + mt) * 16 + ks) << 9) + lane * 8);
  };
  auto ldB = [&](bf16x8 (&d)[4], int ks) {
#pragma unroll
    for (int nt = 0; nt < 4; ++nt)
      d[nt] = *reinterpret_cast<const bf16x8*>(lds + ((((rg * 4 + nt) * 16) + ks) << 9) + lane * 8);
  };
  // store lrelu(acc + bias) into LDS h-panel (b64 packed quads), for next layer
  auto store_h = [&](f32x4 (&a)[8][4], const float* __restrict__ bias) {
#pragma unroll
    for (int mt = 0; mt < 8; ++mt) {
      float4 bv = *reinterpret_cast<const float4*>(bias + fg * 128 + mt * 16 + (lane >> 4) * 4);
      int ks2 = fg * 4 + (mt >> 1);
      int kq2 = (mt & 1) * 2 + ((lane >> 4) >> 1);
#pragma unroll
      for (int nt = 0; nt < 4; ++nt) {
        unsigned int w0 = f2bf(lrelu(a[mt][nt][0] + bv.x));
        unsigned int w1 = f2bf(lrelu(a[mt][nt][1] + bv.y));
        unsigned int w2 = f2bf(lrelu(a[mt][nt][2] + bv.z));
        unsigned int w3 = f2bf(lrelu(a[mt][nt][3] + bv.w));
        uint2 val; val.x = (w1 << 16) | w0; val.y = (w3 << 16) | w2;
        int off = (((rg * 4 + nt) * 16 + ks2) << 9) + kq2 * 128 + l15 * 8 + ((lane >> 4) & 1) * 4;
        *reinterpret_cast<uint2*>(lds + off) = val;
      }
    }
  };
  auto layer = [&](const unsigned short* __restrict__ Wp) {
#pragma unroll
    for (int mt = 0; mt < 8; ++mt)
#pragma unroll
      for (int nt = 0; nt < 4; ++nt) acc[mt][nt] = f32x4{0.f, 0.f, 0.f, 0.f};
    ldA(ca, Wp, 0);
    for (int ks = 0; ks < 16; ++ks) {
      ldA(na, Wp, (ks + 1) & 15);
      ldB(cb, ks);
      __builtin_amdgcn_s_setprio(1);
#pragma unroll
      for (int mt = 0; mt < 8; ++mt)
#pragma unroll
        for (int nt = 0; nt < 4; ++nt)
          acc[mt][nt] = __builtin_amdgcn_mfma_f32_16x16x32_bf16(ca[mt], cb[nt], acc[mt][nt], 0, 0, 0);
      __builtin_amdgcn_s_setprio(0);
#pragma unroll
      for (int q = 0; q < 8; ++q) ca[q] = na[q];
    }
  };

  // ---- layer 2 ----
  layer(W2P);
  __syncthreads();          // all waves done reading h1
  store_h(acc, b2);
  __syncthreads();

  // ---- layer 3 ----
  layer(W3P);
  __syncthreads();          // all waves done reading h2
  store_h(acc, b3);         // store lrelu(h3) for the j-sum
  __syncthreads();

  // ---- j-sum reduction: Msum[token][feat] = sum_j h3[token*16+j][feat] ----
  {
    const int t = wid;             // token 0..7 within block
    const int fb = lane;           // feat block of 8: feats fb*8..fb*8+7
    const int ks = fb >> 2, kq = fb & 3;
    const unsigned short* base = lds + ((t * 16 + ks) << 9) + kq * 128;
    float s[8] = {0.f, 0.f, 0.f, 0.f, 0.f, 0.f, 0.f, 0.f};
    for (int it = 0; it < 16; ++it) {
      int j = (it + lane) & 15;    // rotate to spread banks
      uint4 v = *reinterpret_cast<const uint4*>(base + j * 8);
      s[0] += bflo(v.x); s[1] += bfhi(v.x);
      s[2] += bflo(v.y); s[3] += bfhi(v.y);
      s[4] += bflo(v.z); s[5] += bfhi(v.z);
      s[6] += bflo(v.w); s[7] += bfhi(v.w);
    }
    uint4 o;
    o.x = ((unsigned int)f2bf(s[1]) << 16) | f2bf(s[0]);
    o.y = ((unsigned int)f2bf(s[3]) << 16) | f2bf(s[2]);
    o.z = ((unsigned int)f2bf(s[5]) << 16) | f2bf(s[4]);
    o.w = ((unsigned int)f2bf(s[7]) << 16) | f2bf(s[6]);
    int tg15 = half * 8 + t;       // token within 16-token panel (panel = b)
    *reinterpret_cast<uint4*>(XP + ((b * 32 + 16 + ks) << 9) + kq * 128 + tg15 * 8) = o;
  }
}

// ---- fusion GEMM + BN partial stats. grid (64,4), 512 thr ----
__global__ __launch_bounds__(512) void k_fusion(const unsigned short* __restrict__ XP,
                                                const unsigned short* __restrict__ WfP,
                                                const float* __restrict__ bfv,
                                                float* __restrict__ y,
                                                float* __restrict__ sums,
                                                float* __restrict__ sumsq) {
  const int tid = threadIdx.x, lane = tid & 63, wid = tid >> 6;
  const int wm = wid >> 2, wn = wid & 3;
  const int l15 = lane & 15;
  const int bx = blockIdx.x, by = blockIdx.y;
  const int rowbase = bx * 64 + wm * 32;
  const int colbase = by * 128 + wn * 32;

  f32x4 acc[2][2];
#pragma unroll
  for (int mt = 0; mt < 2; ++mt)
#pragma unroll
    for (int nt = 0; nt < 2; ++nt) acc[mt][nt] = f32x4{0.f, 0.f, 0.f, 0.f};

  bf16x8 ca[2], cb[2], na[2], nb[2];
  auto ldA = [&](bf16x8 (&d)[2], int ks) {
#pragma unroll
    for (int mt = 0; mt < 2; ++mt)
      d[mt] = *reinterpret_cast<const bf16x8*>(XP + (((bx * 4 + wm * 2 + mt) * 32 + ks) << 9) + lane * 8);
  };
  auto ldB = [&](bf16x8 (&d)[2], int ks) {
#pragma unroll
    for (int nt = 0; nt < 2; ++nt)
      d[nt] = *reinterpret_cast<const bf16x8*>(WfP + (((by * 8 + wn * 2 + nt) * 32 + ks) << 9) + lane * 8);
  };

  ldA(ca, 0); ldB(cb, 0);
  for (int ks = 0; ks < 32; ++ks) {
    int kn = (ks + 1) & 31;
    ldA(na, kn); ldB(nb, kn);
    __builtin_amdgcn_s_setprio(1);
#pragma unroll
    for (int mt = 0; mt < 2; ++mt)
#pragma unroll
      for (int nt = 0; nt < 2; ++nt)
        acc[mt][nt] = __builtin_amdgcn_mfma_f32_16x16x32_bf16(ca[mt], cb[nt], acc[mt][nt], 0, 0, 0);
    __builtin_amdgcn_s_setprio(0);
#pragma unroll
    for (int q = 0; q < 2; ++q) { ca[q] = na[q]; cb[q] = nb[q]; }
  }

  float s[2] = {0.f, 0.f}, q2[2] = {0.f, 0.f};
#pragma unroll
  for (int nt = 0; nt < 2; ++nt) {
    int col = colbase + nt * 16 + l15;
    float bias = bfv[col];
#pragma unroll
    for (int mt = 0; mt < 2; ++mt)
#pragma unroll
      for (int r = 0; r < 4; ++r) {
        int row = rowbase + mt * 16 + (lane >> 4) * 4 + r;
        float v = acc[mt][nt][r] + bias;
        y[row * DD + col] = v;
        s[nt] += v; q2[nt] += v * v;
      }
  }
#pragma unroll
  for (int nt = 0; nt < 2; ++nt) {
    s[nt] += __shfl_xor(s[nt], 16);  s[nt] += __shfl_xor(s[nt], 32);
    q2[nt] += __shfl_xor(q2[nt], 16); q2[nt] += __shfl_xor(q2[nt], 32);
    if (lane < 16) {
      int col = colbase + nt * 16 + l15;
      atomicAdd(&sums[col], s[nt]);
      atomicAdd(&sumsq[col], q2[nt]);
    }
  }
}

// ---- BN apply + lrelu ----
__global__ __launch_bounds__(256) void k_bnapply(const float* __restrict__ y,
                                                 const float* __restrict__ sums,
                                                 const float* __restrict__ sumsq,
                                                 const float* __restrict__ gamma,
                                                 const float* __restrict__ beta,
                                                 float* __restrict__ out) {
  int idx = blockIdx.x * 256 + threadIdx.x;
  if (idx >= NTOK * DD) return;
  int c = idx & 511;
  float mean = sums[c] * (1.0f / 4096.0f);
  float var = sumsq[c] * (1.0f / 4096.0f) - mean * mean;
  float rstd = rsqrtf(var + 1e-5f);
  float v = (y[idx] - mean) * rstd * gamma[c] + beta[c];
  out[idx] = lrelu(v);
}

extern "C" void kernel_launch(void* const* d_in, const int* in_sizes, int n_in,
                              void* d_out, int out_size, void* d_ws, size_t ws_size,
                              hipStream_t stream) {
  const float* F   = (const float*)d_in[0];
  const float* W1  = (const float*)d_in[1];
  const float* b1  = (const float*)d_in[2];
  const float* W2  = (const float*)d_in[3];
  const float* b2  = (const float*)d_in[4];
  const float* W3  = (const float*)d_in[5];
  const float* b3  = (const float*)d_in[6];
  const float* Wf  = (const float*)d_in[7];
  const float* bfv = (const float*)d_in[8];
  const float* gamma = (const float*)d_in[9];
  const float* beta  = (const float*)d_in[10];
  float* out = (float*)d_out;

  char* ws = (char*)d_ws;
  unsigned short* XP  = (unsigned short*)(ws);                              // 8 MB panel [F | Msum]
  unsigned short* ACP = (unsigned short*)(ws + (8u << 20));                 // 8 MB panel
  unsigned short* W1P = (unsigned short*)(ws + (16u << 20));                // 1 MB
  unsigned short* W2P = (unsigned short*)(ws + (17u << 20));                // 0.5 MB
  unsigned short* W3P = (unsigned short*)(ws + (17u << 20) + (512u << 10)); // 0.5 MB
  unsigned short* WfP = (unsigned short*)(ws + (18u << 20));                // 1 MB
  float* y            = (float*)(ws + (19u << 20));                         // 8 MB
  float* sums         = (float*)(ws + (27u << 20));                         // 2 KB
  float* sumsq        = sums + 512;                                         // 2 KB

  k_prep<<<14337, 256, 0, stream>>>(F, W1, W2, W3, Wf, XP, W1P, W2P, W3P, WfP, sums);
  k_gemm_ac<<<dim3(64, 4), 512, 0, stream>>>(XP, W1P, ACP);
  k_relation<<<512, 512, 0, stream>>>(ACP, W2P, W3P, b1, b2, b3, XP);
  k_fusion<<<dim3(64, 4), 512, 0, stream>>>(XP, WfP, bfv, y, sums, sumsq);
  k_bnapply<<<(NTOK * DD + 255) / 256, 256, 0, stream>>>(y, sums, sumsq, gamma, beta, out);
}

// Round 5
// 121.851 us; speedup vs baseline: 1.0360x; 1.0360x over previous
//
#include <hip/hip_runtime.h>

using f32x4  = __attribute__((ext_vector_type(4))) float;
using bf16x8 = __attribute__((ext_vector_type(8))) __bf16;

static constexpr int DD = 512;
static constexpr int NTOK = 4096;  // B*V

__device__ __forceinline__ float bf2f(unsigned short u) {
  unsigned int v = ((unsigned int)u) << 16;
  return __builtin_bit_cast(float, v);
}
__device__ __forceinline__ float bflo(unsigned int u) {
  return __builtin_bit_cast(float, u << 16);
}
__device__ __forceinline__ float bfhi(unsigned int u) {
  return __builtin_bit_cast(float, u & 0xffff0000u);
}
__device__ __forceinline__ unsigned short f2bf(float f) {
  unsigned int u = __builtin_bit_cast(unsigned int, f);
  unsigned int r = u + 0x7fffu + ((u >> 16) & 1u);
  return (unsigned short)(r >> 16);
}
__device__ __forceinline__ float lrelu(float v) { return v >= 0.f ? v : 0.2f * v; }

// Fragment-panel layout for (rows,K) consumed as MFMA operand:
// off = (tile16*KS + ks)*512 + ((k>>3)&3)*128 + (row&15)*8 + (k&7)
// A-frag and B-frag have identical linear layouts; wave load = base + lane*16B.

// ---- k_prep: all layout transforms + BN accumulator zeroing, one dispatch ----
__global__ __launch_bounds__(256) void k_prep(const float* __restrict__ F,
                                              const float* __restrict__ W1,
                                              const float* __restrict__ W2,
                                              const float* __restrict__ W3,
                                              const float* __restrict__ Wf,
                                              unsigned short* __restrict__ XP,
                                              unsigned short* __restrict__ W1P,
                                              unsigned short* __restrict__ W2P,
                                              unsigned short* __restrict__ W3P,
                                              unsigned short* __restrict__ WfP,
                                              float* __restrict__ sums) {
  const int bid = blockIdx.x, tid = threadIdx.x;
  if (bid < 8192) {                       // F -> XP (panel layout, ks 0..15 of 32)
    int idx = (bid << 8) + tid;           // 4096*512
    int t = idx >> 9, c = idx & 511;
    XP[((t >> 4) * 32 + (c >> 5)) * 512 + ((c >> 3) & 3) * 128 + (t & 15) * 8 + (c & 7)] = f2bf(F[idx]);
  } else if (bid < 10240) {               // W1 (1024,512) -> W1P fragment order (K=512, N=1024 combined)
    int idx = ((bid - 8192) << 8) + tid;  // 512*1024
    int k = idx >> 10, n = idx & 1023;
    float v = W1[(n < 512 ? k : 512 + k) * 512 + (n & 511)];
    W1P[((n >> 4) * 16 + (k >> 5)) * 512 + ((k >> 3) & 3) * 128 + (n & 15) * 8 + (k & 7)] = f2bf(v);
  } else if (bid < 11264) {               // W2 (512,512) -> W2P
    int idx = ((bid - 10240) << 8) + tid;
    int k = idx >> 9, n = idx & 511;
    W2P[((n >> 4) * 16 + (k >> 5)) * 512 + ((k >> 3) & 3) * 128 + (n & 15) * 8 + (k & 7)] = f2bf(W2[idx]);
  } else if (bid < 12288) {               // W3
    int idx = ((bid - 11264) << 8) + tid;
    int k = idx >> 9, n = idx & 511;
    W3P[((n >> 4) * 16 + (k >> 5)) * 512 + ((k >> 3) & 3) * 128 + (n & 15) * 8 + (k & 7)] = f2bf(W3[idx]);
  } else if (bid < 14336) {               // Wf (1024,512) -> WfP (K=1024)
    int idx = ((bid - 12288) << 8) + tid;
    int k = idx >> 9, n = idx & 511;
    WfP[((n >> 4) * 32 + (k >> 5)) * 512 + ((k >> 3) & 3) * 128 + (n & 15) * 8 + (k & 7)] = f2bf(Wf[idx]);
  } else {                                // zero sums+sumsq (1024 floats)
    reinterpret_cast<float4*>(sums)[tid] = float4{0.f, 0.f, 0.f, 0.f};
  }
}

// ---- GEMM1: ACP = [F@W1a | F@W1b] in panel layout. grid (64,4), 512 thr ----
__global__ __launch_bounds__(512) void k_gemm_ac(const unsigned short* __restrict__ XP,
                                                 const unsigned short* __restrict__ W1P,
                                                 unsigned short* __restrict__ ACP) {
  const int tid = threadIdx.x, lane = tid & 63, wid = tid >> 6;
  const int wm = wid >> 2, wn = wid & 3;
  const int l15 = lane & 15;
  const int bx = blockIdx.x, by = blockIdx.y;

  f32x4 acc[2][4];
#pragma unroll
  for (int mt = 0; mt < 2; ++mt)
#pragma unroll
    for (int nt = 0; nt < 4; ++nt) acc[mt][nt] = f32x4{0.f, 0.f, 0.f, 0.f};

  bf16x8 ca[2], cb[4], na[2], nb[4];
  auto ldA = [&](bf16x8 (&d)[2], int ks) {
#pragma unroll
    for (int mt = 0; mt < 2; ++mt)
      d[mt] = *reinterpret_cast<const bf16x8*>(XP + (((bx * 4 + wm * 2 + mt) * 32 + ks) << 9) + lane * 8);
  };
  auto ldB = [&](bf16x8 (&d)[4], int ks) {
#pragma unroll
    for (int nt = 0; nt < 4; ++nt)
      d[nt] = *reinterpret_cast<const bf16x8*>(W1P + ((((by * 16 + wn * 4 + nt) * 16) + ks) << 9) + lane * 8);
  };

  ldA(ca, 0); ldB(cb, 0);
  for (int ks = 0; ks < 16; ++ks) {
    int kn = (ks + 1) & 15;
    ldA(na, kn); ldB(nb, kn);
    __builtin_amdgcn_s_setprio(1);
#pragma unroll
    for (int mt = 0; mt < 2; ++mt)
#pragma unroll
      for (int nt = 0; nt < 4; ++nt)
        acc[mt][nt] = __builtin_amdgcn_mfma_f32_16x16x32_bf16(ca[mt], cb[nt], acc[mt][nt], 0, 0, 0);
    __builtin_amdgcn_s_setprio(0);
#pragma unroll
    for (int q = 0; q < 2; ++q) ca[q] = na[q];
#pragma unroll
    for (int q = 0; q < 4; ++q) cb[q] = nb[q];
  }
#pragma unroll
  for (int mt = 0; mt < 2; ++mt)
#pragma unroll
    for (int nt = 0; nt < 4; ++nt) {
      int col = by * 256 + wn * 64 + nt * 16 + l15;
      int panel = bx * 4 + wm * 2 + mt;
#pragma unroll
      for (int r = 0; r < 4; ++r) {
        int rowi = (lane >> 4) * 4 + r;
        ACP[(panel * 32 + (col >> 5)) * 512 + ((col >> 3) & 3) * 128 + rowi * 8 + (col & 7)] = f2bf(acc[mt][nt][r]);
      }
    }
}

// ---- relation: block = (b, half) -> 8 tokens x 16 j = 128 relrows ----
// Operand-swapped: h2^T = W2^T @ h1^T. Wave grid: fg=8 (64 feats each), rg=1
// (every wave covers all 128 relrows). W global traffic dedup'd (dup=1);
// binding pipe becomes LDS reads (~768cy/k-step) > global (~512) > MFMA (~310).
__global__ __launch_bounds__(512, 2) void k_relation(const unsigned short* __restrict__ ACP,
                                                     const unsigned short* __restrict__ W2P,
                                                     const unsigned short* __restrict__ W3P,
                                                     const float* __restrict__ b1,
                                                     const float* __restrict__ b2,
                                                     const float* __restrict__ b3,
                                                     unsigned short* __restrict__ XP) {
  __shared__ unsigned short lds[65536];  // 8 relrow-tiles x 16 ks x 512 el = 128 KB
  const int tid = threadIdx.x;
  const int b = blockIdx.x >> 1, half = blockIdx.x & 1;

  // ---- phase 0: h1 = lrelu(A_i + C_j + b1) -> LDS panel ----
  {
    const int r = tid >> 2;              // relrow 0..127 = il*16 + j
    const int il = r >> 4, j = r & 15;
    const int rowA = half * 8 + il;
    const int kq = tid & 3;
#pragma unroll
    for (int ks = 0; ks < 16; ++ks) {
      const int c = ks * 32 + kq * 8;
      uint4 av = *reinterpret_cast<const uint4*>(ACP + ((b * 32 + ks) << 9) + kq * 128 + rowA * 8);
      uint4 cv = *reinterpret_cast<const uint4*>(ACP + ((b * 32 + 16 + ks) << 9) + kq * 128 + j * 8);
      float4 bv0 = *reinterpret_cast<const float4*>(b1 + c);
      float4 bv1 = *reinterpret_cast<const float4*>(b1 + c + 4);
      unsigned int au[4] = {av.x, av.y, av.z, av.w};
      unsigned int cu[4] = {cv.x, cv.y, cv.z, cv.w};
      float bb[8] = {bv0.x, bv0.y, bv0.z, bv0.w, bv1.x, bv1.y, bv1.z, bv1.w};
      unsigned int ou[4];
#pragma unroll
      for (int q = 0; q < 4; ++q) {
        float v0 = lrelu(bflo(au[q]) + bflo(cu[q]) + bb[2 * q]);
        float v1 = lrelu(bf2f((unsigned short)(au[q] >> 16)) +
                         bf2f((unsigned short)(cu[q] >> 16)) + bb[2 * q + 1]);
        ou[q] = ((unsigned int)f2bf(v1) << 16) | (unsigned int)f2bf(v0);
      }
      uint4 o; o.x = ou[0]; o.y = ou[1]; o.z = ou[2]; o.w = ou[3];
      *reinterpret_cast<uint4*>(lds + (((r >> 4) * 16 + ks) << 9) + kq * 128 + (r & 15) * 8) = o;
    }
  }
  __syncthreads();

  const int lane = tid & 63, wid = tid >> 6;
  const int l15 = lane & 15;
  const int fg = wid;          // feature group 0..7 (64 feats each), rg=1

  f32x4 acc[4][8];
  bf16x8 ca[4], na[4], cb[8];

  auto ldA = [&](bf16x8 (&d)[4], const unsigned short* __restrict__ Wp, int ks) {
#pragma unroll
    for (int mt = 0; mt < 4; ++mt)
      d[mt] = *reinterpret_cast<const bf16x8*>(Wp + (((fg * 4 + mt) * 16 + ks) << 9) + lane * 8);
  };
  auto ldB = [&](bf16x8 (&d)[8], int ks) {
#pragma unroll
    for (int nt = 0; nt < 8; ++nt)
      d[nt] = *reinterpret_cast<const bf16x8*>(lds + (((nt * 16) + ks) << 9) + lane * 8);
  };
  // store lrelu(acc + bias) into LDS h-panel (b64 packed quads), for next layer
  auto store_h = [&](f32x4 (&a)[4][8], const float* __restrict__ bias) {
#pragma unroll
    for (int mt = 0; mt < 4; ++mt) {
      float4 bv = *reinterpret_cast<const float4*>(bias + fg * 64 + mt * 16 + (lane >> 4) * 4);
      int ks2 = fg * 2 + (mt >> 1);
      int kq2 = (mt & 1) * 2 + ((lane >> 4) >> 1);
#pragma unroll
      for (int nt = 0; nt < 8; ++nt) {
        unsigned int w0 = f2bf(lrelu(a[mt][nt][0] + bv.x));
        unsigned int w1 = f2bf(lrelu(a[mt][nt][1] + bv.y));
        unsigned int w2 = f2bf(lrelu(a[mt][nt][2] + bv.z));
        unsigned int w3 = f2bf(lrelu(a[mt][nt][3] + bv.w));
        uint2 val; val.x = (w1 << 16) | w0; val.y = (w3 << 16) | w2;
        int off = ((nt * 16 + ks2) << 9) + kq2 * 128 + l15 * 8 + ((lane >> 4) & 1) * 4;
        *reinterpret_cast<uint2*>(lds + off) = val;
      }
    }
  };
  auto layer = [&](const unsigned short* __restrict__ Wp) {
#pragma unroll
    for (int mt = 0; mt < 4; ++mt)
#pragma unroll
      for (int nt = 0; nt < 8; ++nt) acc[mt][nt] = f32x4{0.f, 0.f, 0.f, 0.f};
    ldA(ca, Wp, 0);
    for (int ks = 0; ks < 16; ++ks) {
      ldA(na, Wp, (ks + 1) & 15);
      ldB(cb, ks);
      __builtin_amdgcn_s_setprio(1);
#pragma unroll
      for (int mt = 0; mt < 4; ++mt)
#pragma unroll
        for (int nt = 0; nt < 8; ++nt)
          acc[mt][nt] = __builtin_amdgcn_mfma_f32_16x16x32_bf16(ca[mt], cb[nt], acc[mt][nt], 0, 0, 0);
      __builtin_amdgcn_s_setprio(0);
#pragma unroll
      for (int q = 0; q < 4; ++q) ca[q] = na[q];
    }
  };

  // ---- layer 2 ----
  layer(W2P);
  __syncthreads();          // all waves done reading h1
  store_h(acc, b2);
  __syncthreads();

  // ---- layer 3 ----
  layer(W3P);
  __syncthreads();          // all waves done reading h2
  store_h(acc, b3);         // store lrelu(h3) for the j-sum
  __syncthreads();

  // ---- j-sum reduction: Msum[token][feat] = sum_j h3[token*16+j][feat] ----
  {
    const int t = wid;             // token 0..7 within block
    const int fb = lane;           // feat block of 8: feats fb*8..fb*8+7
    const int ks = fb >> 2, kq = fb & 3;
    const unsigned short* base = lds + ((t * 16 + ks) << 9) + kq * 128;
    float s[8] = {0.f, 0.f, 0.f, 0.f, 0.f, 0.f, 0.f, 0.f};
    for (int it = 0; it < 16; ++it) {
      int j = (it + lane) & 15;    // rotate to spread banks
      uint4 v = *reinterpret_cast<const uint4*>(base + j * 8);
      s[0] += bflo(v.x); s[1] += bfhi(v.x);
      s[2] += bflo(v.y); s[3] += bfhi(v.y);
      s[4] += bflo(v.z); s[5] += bfhi(v.z);
      s[6] += bflo(v.w); s[7] += bfhi(v.w);
    }
    uint4 o;
    o.x = ((unsigned int)f2bf(s[1]) << 16) | f2bf(s[0]);
    o.y = ((unsigned int)f2bf(s[3]) << 16) | f2bf(s[2]);
    o.z = ((unsigned int)f2bf(s[5]) << 16) | f2bf(s[4]);
    o.w = ((unsigned int)f2bf(s[7]) << 16) | f2bf(s[6]);
    int tg15 = half * 8 + t;       // token within 16-token panel (panel = b)
    *reinterpret_cast<uint4*>(XP + ((b * 32 + 16 + ks) << 9) + kq * 128 + tg15 * 8) = o;
  }
}

// ---- fusion GEMM + BN partial stats. grid (64,4), 512 thr ----
__global__ __launch_bounds__(512) void k_fusion(const unsigned short* __restrict__ XP,
                                                const unsigned short* __restrict__ WfP,
                                                const float* __restrict__ bfv,
                                                float* __restrict__ y,
                                                float* __restrict__ sums,
                                                float* __restrict__ sumsq) {
  const int tid = threadIdx.x, lane = tid & 63, wid = tid >> 6;
  const int wm = wid >> 2, wn = wid & 3;
  const int l15 = lane & 15;
  const int bx = blockIdx.x, by = blockIdx.y;
  const int rowbase = bx * 64 + wm * 32;
  const int colbase = by * 128 + wn * 32;

  f32x4 acc[2][2];
#pragma unroll
  for (int mt = 0; mt < 2; ++mt)
#pragma unroll
    for (int nt = 0; nt < 2; ++nt) acc[mt][nt] = f32x4{0.f, 0.f, 0.f, 0.f};

  bf16x8 ca[2], cb[2], na[2], nb[2];
  auto ldA = [&](bf16x8 (&d)[2], int ks) {
#pragma unroll
    for (int mt = 0; mt < 2; ++mt)
      d[mt] = *reinterpret_cast<const bf16x8*>(XP + (((bx * 4 + wm * 2 + mt) * 32 + ks) << 9) + lane * 8);
  };
  auto ldB = [&](bf16x8 (&d)[2], int ks) {
#pragma unroll
    for (int nt = 0; nt < 2; ++nt)
      d[nt] = *reinterpret_cast<const bf16x8*>(WfP + (((by * 8 + wn * 2 + nt) * 32 + ks) << 9) + lane * 8);
  };

  ldA(ca, 0); ldB(cb, 0);
  for (int ks = 0; ks < 32; ++ks) {
    int kn = (ks + 1) & 31;
    ldA(na, kn); ldB(nb, kn);
    __builtin_amdgcn_s_setprio(1);
#pragma unroll
    for (int mt = 0; mt < 2; ++mt)
#pragma unroll
      for (int nt = 0; nt < 2; ++nt)
        acc[mt][nt] = __builtin_amdgcn_mfma_f32_16x16x32_bf16(ca[mt], cb[nt], acc[mt][nt], 0, 0, 0);
    __builtin_amdgcn_s_setprio(0);
#pragma unroll
    for (int q = 0; q < 2; ++q) { ca[q] = na[q]; cb[q] = nb[q]; }
  }

  float s[2] = {0.f, 0.f}, q2[2] = {0.f, 0.f};
#pragma unroll
  for (int nt = 0; nt < 2; ++nt) {
    int col = colbase + nt * 16 + l15;
    float bias = bfv[col];
#pragma unroll
    for (int mt = 0; mt < 2; ++mt)
#pragma unroll
      for (int r = 0; r < 4; ++r) {
        int row = rowbase + mt * 16 + (lane >> 4) * 4 + r;
        float v = acc[mt][nt][r] + bias;
        y[row * DD + col] = v;
        s[nt] += v; q2[nt] += v * v;
      }
  }
#pragma unroll
  for (int nt = 0; nt < 2; ++nt) {
    s[nt] += __shfl_xor(s[nt], 16);  s[nt] += __shfl_xor(s[nt], 32);
    q2[nt] += __shfl_xor(q2[nt], 16); q2[nt] += __shfl_xor(q2[nt], 32);
    if (lane < 16) {
      int col = colbase + nt * 16 + l15;
      atomicAdd(&sums[col], s[nt]);
      atomicAdd(&sumsq[col], q2[nt]);
    }
  }
}

// ---- BN apply + lrelu ----
__global__ __launch_bounds__(256) void k_bnapply(const float* __restrict__ y,
                                                 const float* __restrict__ sums,
                                                 const float* __restrict__ sumsq,
                                                 const float* __restrict__ gamma,
                                                 const float* __restrict__ beta,
                                                 float* __restrict__ out) {
  int idx = blockIdx.x * 256 + threadIdx.x;
  if (idx >= NTOK * DD) return;
  int c = idx & 511;
  float mean = sums[c] * (1.0f / 4096.0f);
  float var = sumsq[c] * (1.0f / 4096.0f) - mean * mean;
  float rstd = rsqrtf(var + 1e-5f);
  float v = (y[idx] - mean) * rstd * gamma[c] + beta[c];
  out[idx] = lrelu(v);
}

extern "C" void kernel_launch(void* const* d_in, const int* in_sizes, int n_in,
                              void* d_out, int out_size, void* d_ws, size_t ws_size,
                              hipStream_t stream) {
  const float* F   = (const float*)d_in[0];
  const float* W1  = (const float*)d_in[1];
  const float* b1  = (const float*)d_in[2];
  const float* W2  = (const float*)d_in[3];
  const float* b2  = (const float*)d_in[4];
  const float* W3  = (const float*)d_in[5];
  const float* b3  = (const float*)d_in[6];
  const float* Wf  = (const float*)d_in[7];
  const float* bfv = (const float*)d_in[8];
  const float* gamma = (const float*)d_in[9];
  const float* beta  = (const float*)d_in[10];
  float* out = (float*)d_out;

  char* ws = (char*)d_ws;
  unsigned short* XP  = (unsigned short*)(ws);                              // 8 MB panel [F | Msum]
  unsigned short* ACP = (unsigned short*)(ws + (8u << 20));                 // 8 MB panel
  unsigned short* W1P = (unsigned short*)(ws + (16u << 20));                // 1 MB
  unsigned short* W2P = (unsigned short*)(ws + (17u << 20));                // 0.5 MB
  unsigned short* W3P = (unsigned short*)(ws + (17u << 20) + (512u << 10)); // 0.5 MB
  unsigned short* WfP = (unsigned short*)(ws + (18u << 20));                // 1 MB
  float* y            = (float*)(ws + (19u << 20));                         // 8 MB
  float* sums         = (float*)(ws + (27u << 20));                         // 2 KB
  float* sumsq        = sums + 512;                                         // 2 KB

  k_prep<<<14337, 256, 0, stream>>>(F, W1, W2, W3, Wf, XP, W1P, W2P, W3P, WfP, sums);
  k_gemm_ac<<<dim3(64, 4), 512, 0, stream>>>(XP, W1P, ACP);
  k_relation<<<512, 512, 0, stream>>>(ACP, W2P, W3P, b1, b2, b3, XP);
  k_fusion<<<dim3(64, 4), 512, 0, stream>>>(XP, WfP, bfv, y, sums, sumsq);
  k_bnapply<<<(NTOK * DD + 255) / 256, 256, 0, stream>>>(y, sums, sumsq, gamma, beta, out);
}